// Round 6
// baseline (384.557 us; speedup 1.0000x reference)
//
#include <hip/hip_runtime.h>

#define N_NODES 100000
#define N_EDGES 1200000
#define DIM 64
#define SCAN_BLOCK 256
#define NB ((N_NODES + SCAN_BLOCK - 1) / SCAN_BLOCK)  // 391
#define NSHARD 8
#define NQUADS (N_EDGES / 4)  // 300000, exact
#define CAP 40  // padded-CSR row capacity; P(deg>=40 | Poisson(12)) ~1e-11/node

__device__ __forceinline__ float lane_bcast(float v, int k) {
  return __int_as_float(__builtin_amdgcn_readlane(__float_as_int(v), k));
}

// butterfly-sum a float4 across the four 16-lane groups (xor 16, then 32)
__device__ __forceinline__ float4 qsum(float4 v) {
  v.x += __shfl_xor(v.x, 16); v.y += __shfl_xor(v.y, 16);
  v.z += __shfl_xor(v.z, 16); v.w += __shfl_xor(v.w, 16);
  v.x += __shfl_xor(v.x, 32); v.y += __shfl_xor(v.y, 32);
  v.z += __shfl_xor(v.z, 32); v.w += __shfl_xor(v.w, 32);
  return v;
}

// ---- PADDED CSR build: offsets COMPUTED (row n = n*CAP); no hist/scan.
// cnt doubles as cursor and degree. csr_pad pre-zeroed so clamped reads of
// unwritten slots return src=0 (valid node, value discarded via scale=0). ---

__global__ __launch_bounds__(256) void fill_csr_pad(
    const int4* __restrict__ src4, const int4* __restrict__ dst4,
    int* __restrict__ cnt, int* __restrict__ csr_pad, int nQuads) {
  int t = blockIdx.x * blockDim.x + threadIdx.x;
  if (t < nQuads) {
    int4 sv = src4[t];
    int4 dv = dst4[t];
    int p;
    p = atomicAdd(&cnt[dv.x], 1); if (p < CAP) csr_pad[dv.x * CAP + p] = sv.x;
    p = atomicAdd(&cnt[dv.y], 1); if (p < CAP) csr_pad[dv.y * CAP + p] = sv.y;
    p = atomicAdd(&cnt[dv.z], 1); if (p < CAP) csr_pad[dv.z * CAP + p] = sv.z;
    p = atomicAdd(&cnt[dv.w], 1); if (p < CAP) csr_pad[dv.w * CAP + p] = sv.w;
  }
}

// ---- LEGACY CSR build (fallback if ws_size too small for padded layout) ---

__global__ __launch_bounds__(256) void hist_deg_s(
    const int4* __restrict__ dst4, int* __restrict__ deg_s, int nQuads) {
  int t = blockIdx.x * blockDim.x + threadIdx.x;
  int shard = blockIdx.x & (NSHARD - 1);
  if (t < nQuads) {
    int4 d = dst4[t];
    int* tbl = deg_s + (size_t)shard * N_NODES;
    atomicAdd(&tbl[d.x], 1);
    atomicAdd(&tbl[d.y], 1);
    atomicAdd(&tbl[d.z], 1);
    atomicAdd(&tbl[d.w], 1);
  }
}

__global__ __launch_bounds__(SCAN_BLOCK) void block_sums(
    const int* __restrict__ deg_s, int* __restrict__ bsums, int n) {
  __shared__ int s[SCAN_BLOCK];
  int i = blockIdx.x * SCAN_BLOCK + threadIdx.x;
  int d = 0;
  if (i < n) {
#pragma unroll
    for (int sh = 0; sh < NSHARD; ++sh) d += deg_s[(size_t)sh * N_NODES + i];
  }
  s[threadIdx.x] = d;
  __syncthreads();
  for (int off = SCAN_BLOCK / 2; off > 0; off >>= 1) {
    if (threadIdx.x < off) s[threadIdx.x] += s[threadIdx.x + off];
    __syncthreads();
  }
  if (threadIdx.x == 0) bsums[blockIdx.x] = s[0];
}

__global__ __launch_bounds__(512) void scan_bsums(int* __restrict__ bsums, int nb) {
  __shared__ int s[512];
  int tid = threadIdx.x;
  s[tid] = (tid < nb) ? bsums[tid] : 0;
  __syncthreads();
  for (int off = 1; off < 512; off <<= 1) {
    int v = (tid >= off) ? s[tid - off] : 0;
    __syncthreads();
    s[tid] += v;
    __syncthreads();
  }
  if (tid < nb) bsums[tid] = (tid == 0) ? 0 : s[tid - 1];  // exclusive base
}

__global__ __launch_bounds__(SCAN_BLOCK) void scan_final(
    const int* __restrict__ deg_s, const int* __restrict__ bbase,
    int* __restrict__ offs, int* __restrict__ cursor_s, int n) {
  __shared__ int s[SCAN_BLOCK];
  int i = blockIdx.x * SCAN_BLOCK + threadIdx.x;
  int ds0 = 0, ds1 = 0, ds2 = 0, ds3 = 0, ds4 = 0, ds5 = 0, ds6 = 0, ds7 = 0;
  int v = 0;
  if (i < n) {
    ds0 = deg_s[0ul * N_NODES + i]; ds1 = deg_s[1ul * N_NODES + i];
    ds2 = deg_s[2ul * N_NODES + i]; ds3 = deg_s[3ul * N_NODES + i];
    ds4 = deg_s[4ul * N_NODES + i]; ds5 = deg_s[5ul * N_NODES + i];
    ds6 = deg_s[6ul * N_NODES + i]; ds7 = deg_s[7ul * N_NODES + i];
    v = ((ds0 + ds1) + (ds2 + ds3)) + ((ds4 + ds5) + (ds6 + ds7));
  }
  s[threadIdx.x] = v;
  __syncthreads();
  for (int off = 1; off < SCAN_BLOCK; off <<= 1) {
    int t = (threadIdx.x >= off) ? s[threadIdx.x - off] : 0;
    __syncthreads();
    s[threadIdx.x] += t;
    __syncthreads();
  }
  int base = bbase[blockIdx.x];
  if (i < n) {
    int run = base + s[threadIdx.x] - v;  // exclusive
    offs[i] = run;
    cursor_s[0ul * N_NODES + i] = run; run += ds0;
    cursor_s[1ul * N_NODES + i] = run; run += ds1;
    cursor_s[2ul * N_NODES + i] = run; run += ds2;
    cursor_s[3ul * N_NODES + i] = run; run += ds3;
    cursor_s[4ul * N_NODES + i] = run; run += ds4;
    cursor_s[5ul * N_NODES + i] = run; run += ds5;
    cursor_s[6ul * N_NODES + i] = run; run += ds6;
    cursor_s[7ul * N_NODES + i] = run;
  }
  if (i == n - 1) offs[n] = base + s[threadIdx.x];
}

__global__ __launch_bounds__(256) void fill_csr_s(
    const int4* __restrict__ src4, const int4* __restrict__ dst4,
    int* __restrict__ cursor_s, int* __restrict__ csr_src, int nQuads) {
  int t = blockIdx.x * blockDim.x + threadIdx.x;
  int shard = blockIdx.x & (NSHARD - 1);
  if (t < nQuads) {
    int4 sv = src4[t];
    int4 dv = dst4[t];
    int* cur = cursor_s + (size_t)shard * N_NODES;
    csr_src[atomicAdd(&cur[dv.x], 1)] = sv.x;
    csr_src[atomicAdd(&cur[dv.y], 1)] = sv.y;
    csr_src[atomicAdd(&cur[dv.z], 1)] = sv.z;
    csr_src[atomicAdd(&cur[dv.w], 1)] = sv.w;
  }
}

// ---- Fused SAGE layer v12 -------------------------------------------------
// Gather: wave = (q=lane>>4, r=lane&15); 2x-unrolled -> 8 edges/node/iter in
// flight + software-pipelined csr prefetch; branch-free mean fold.
// ROUND-6 CHANGE: the shfl/csel transpose stage is GONE — after qsum every
// lane holds the full mean float4 for dims [4r,4r+4), so the matvec
// readlane sources component (k&3) of A/B directly at lane (k>>2)
// (compile-time component select in the unrolled loop). One less dependent
// cross-lane stage before the matvec can issue.
// ROUND-2 LESSON: never use the min-waves arg of __launch_bounds__.
// ROUND-3 LESSON: no occupancy/query APIs inside kernel_launch.
// ROUND-6/7 LESSON: no indexed private arrays, ever.
// Occupancy box: LDS 32768 B -> 5 blocks/CU; VGPR must stay <= 102.
template <bool PADDED>
__global__ __launch_bounds__(256) void sage_fused(
    const float* __restrict__ xin, const int* __restrict__ offs_or_cnt,
    const int* __restrict__ csr_src, const float* __restrict__ Wn,
    const float* __restrict__ Ws, const float* __restrict__ bias,
    float* __restrict__ out, int nNodes) {
  __shared__ float2 sW[DIM * DIM];  // [k][j] -> (wn, ws), 32768 B exactly
  {
    const float4* Wn4 = reinterpret_cast<const float4*>(Wn);
    const float4* Ws4 = reinterpret_cast<const float4*>(Ws);
    for (int i = threadIdx.x; i < DIM * DIM / 4; i += 256) {
      float4 a = Wn4[i];
      float4 b = Ws4[i];
      float2* d = &sW[i * 4];  // i = k*16 + jq -> element k*64 + 4*jq
      d[0] = make_float2(a.x, b.x);
      d[1] = make_float2(a.y, b.y);
      d[2] = make_float2(a.z, b.z);
      d[3] = make_float2(a.w, b.w);
    }
  }
  __syncthreads();

  const float4* xr = reinterpret_cast<const float4*>(xin);
  int lane = threadIdx.x & 63;
  int q = lane >> 4;   // edge subgroup 0..3
  int r = lane & 15;   // float4 column 0..15
  int j = lane;        // output dim
  int w = threadIdx.x >> 6;
  float bj = bias[j];
  int gw = blockIdx.x * 4 + w;
  int nw = gridDim.x * 4;

  for (int p = gw; 2 * p < nNodes; p += nw) {
    int pu = __builtin_amdgcn_readfirstlane(p);  // wave-uniform -> s_loads
    int n0 = 2 * pu, n1 = 2 * pu + 1;
    int e0a, e1a, e0b, e1b;
    float inv0, inv1;
    if (PADDED) {
      int d0 = offs_or_cnt[n0], d1 = offs_or_cnt[n1];
      e0a = n0 * CAP; e1a = e0a + min(d0, CAP);
      e0b = e0a + CAP; e1b = e0b + min(d1, CAP);
      inv0 = 1.0f / fmaxf((float)d0, 1.0f);  // true count, matches reference
      inv1 = 1.0f / fmaxf((float)d1, 1.0f);
    } else {
      e0a = offs_or_cnt[n0]; e0b = offs_or_cnt[n1]; e1b = offs_or_cnt[n1 + 1];
      e1a = e0b;  // offs[n0+1] == offs[n1]
      inv0 = 1.0f / fmaxf((float)(e1a - e0a), 1.0f);
      inv1 = 1.0f / fmaxf((float)(e1b - e0b), 1.0f);
    }
    float self0 = xin[(size_t)n0 * DIM + j];
    float self1 = xin[(size_t)n1 * DIM + j];

    float4 A = {0, 0, 0, 0}, B = {0, 0, 0, 0};
    int ea0 = e0a + q, ea1 = e0a + q + 4;
    int eb0 = e0b + q, eb1 = e0b + q + 4;
    int rem = max(e1a - e0a, e1b - e0b);
    // prologue: csr index loads for iteration 0 (clamped -> always valid)
    int sa0 = csr_src[max(min(ea0, e1a - 1), 0)];
    int sa1 = csr_src[max(min(ea1, e1a - 1), 0)];
    int sb0 = csr_src[max(min(eb0, e1b - 1), 0)];
    int sb1 = csr_src[max(min(eb1, e1b - 1), 0)];
    while (rem > 0) {
      // issue all 8 x-row gathers for the current 8 edges
      float4 va0 = xr[(size_t)sa0 * 16 + r];
      float4 va1 = xr[(size_t)sa1 * 16 + r];
      float4 vb0 = xr[(size_t)sb0 * 16 + r];
      float4 vb1 = xr[(size_t)sb1 * 16 + r];
      float fa0 = (ea0 < e1a) ? inv0 : 0.0f;
      float fa1 = (ea1 < e1a) ? inv0 : 0.0f;
      float fb0 = (eb0 < e1b) ? inv1 : 0.0f;
      float fb1 = (eb1 < e1b) ? inv1 : 0.0f;
      ea0 += 8; ea1 += 8; eb0 += 8; eb1 += 8; rem -= 8;
      // prefetch next iteration's csr indices while x rows are in flight
      int na0 = csr_src[max(min(ea0, e1a - 1), 0)];
      int na1 = csr_src[max(min(ea1, e1a - 1), 0)];
      int nb0 = csr_src[max(min(eb0, e1b - 1), 0)];
      int nb1 = csr_src[max(min(eb1, e1b - 1), 0)];
      A.x = fmaf(va0.x, fa0, A.x); A.y = fmaf(va0.y, fa0, A.y);
      A.z = fmaf(va0.z, fa0, A.z); A.w = fmaf(va0.w, fa0, A.w);
      A.x = fmaf(va1.x, fa1, A.x); A.y = fmaf(va1.y, fa1, A.y);
      A.z = fmaf(va1.z, fa1, A.z); A.w = fmaf(va1.w, fa1, A.w);
      B.x = fmaf(vb0.x, fb0, B.x); B.y = fmaf(vb0.y, fb0, B.y);
      B.z = fmaf(vb0.z, fb0, B.z); B.w = fmaf(vb0.w, fb0, B.w);
      B.x = fmaf(vb1.x, fb1, B.x); B.y = fmaf(vb1.y, fb1, B.y);
      B.z = fmaf(vb1.z, fb1, B.z); B.w = fmaf(vb1.w, fb1, B.w);
      sa0 = na0; sa1 = na1; sb0 = nb0; sb1 = nb1;
    }
    A = qsum(A);  // every lane now holds the FULL mean for dims [4r,4r+4)
    B = qsum(B);

    // matvec: 4 independent chains; ONE b64 weight read per k; mean sourced
    // straight from A/B via readlane (lane k>>2, component k&3 — both
    // compile-time in the unrolled loop). No transpose stage.
    float a0n = bj, a0s = 0.f, a1n = bj, a1s = 0.f;
#pragma unroll
    for (int kk = 0; kk < DIM / 4; ++kk) {
      {
        float2 wk = sW[(4 * kk + 0) * DIM + j];
        a0n = fmaf(lane_bcast(A.x, kk), wk.x, a0n);
        a0s = fmaf(lane_bcast(self0, 4 * kk + 0), wk.y, a0s);
        a1n = fmaf(lane_bcast(B.x, kk), wk.x, a1n);
        a1s = fmaf(lane_bcast(self1, 4 * kk + 0), wk.y, a1s);
      }
      {
        float2 wk = sW[(4 * kk + 1) * DIM + j];
        a0n = fmaf(lane_bcast(A.y, kk), wk.x, a0n);
        a0s = fmaf(lane_bcast(self0, 4 * kk + 1), wk.y, a0s);
        a1n = fmaf(lane_bcast(B.y, kk), wk.x, a1n);
        a1s = fmaf(lane_bcast(self1, 4 * kk + 1), wk.y, a1s);
      }
      {
        float2 wk = sW[(4 * kk + 2) * DIM + j];
        a0n = fmaf(lane_bcast(A.z, kk), wk.x, a0n);
        a0s = fmaf(lane_bcast(self0, 4 * kk + 2), wk.y, a0s);
        a1n = fmaf(lane_bcast(B.z, kk), wk.x, a1n);
        a1s = fmaf(lane_bcast(self1, 4 * kk + 2), wk.y, a1s);
      }
      {
        float2 wk = sW[(4 * kk + 3) * DIM + j];
        a0n = fmaf(lane_bcast(A.w, kk), wk.x, a0n);
        a0s = fmaf(lane_bcast(self0, 4 * kk + 3), wk.y, a0s);
        a1n = fmaf(lane_bcast(B.w, kk), wk.x, a1n);
        a1s = fmaf(lane_bcast(self1, 4 * kk + 3), wk.y, a1s);
      }
    }
    out[(size_t)n0 * DIM + j] = fmaxf(a0n + a0s, 0.0f);
    out[(size_t)n1 * DIM + j] = fmaxf(a1n + a1s, 0.0f);
  }
}

// Residency ground truth, queried ONCE at library load — before any stream
// capture exists (round-3 lesson). Both instantiations share the footprint.
static int g_fusedBlocks = 0;
__attribute__((constructor)) static void init_fused_blocks() {
  int occ = 0;
  if (hipOccupancyMaxActiveBlocksPerMultiprocessor(&occ, sage_fused<true>, 256, 0)
          != hipSuccess || occ < 1)
    occ = 4;  // conservative fallback: 4/CU always resident
  g_fusedBlocks = occ * 256;  // blocks/CU * 256 CUs, all resident at t=0
}

extern "C" void kernel_launch(void* const* d_in, const int* in_sizes, int n_in,
                              void* d_out, int out_size, void* d_ws, size_t ws_size,
                              hipStream_t stream) {
  const float* x   = (const float*)d_in[0];
  const int*   ei  = (const int*)d_in[1];
  const float* Wn1 = (const float*)d_in[2];
  const float* Ws1 = (const float*)d_in[3];
  const float* b1  = (const float*)d_in[4];
  const float* Wn2 = (const float*)d_in[5];
  const float* Ws2 = (const float*)d_in[6];
  const float* b2  = (const float*)d_in[7];
  const int* src = ei;
  const int* dst = ei + N_EDGES;

  const int quadBlocks = (NQUADS + 255) / 256;  // 1172
  const int fusedBlocks = (g_fusedBlocks > 0) ? g_fusedBlocks : 1024;
  float* outp = (float*)d_out;

  // Padded layout (ints): cnt[N] | csr_pad[N*CAP] | h1[N*64]f
  const size_t padInts = (size_t)N_NODES + (size_t)N_NODES * CAP;
  const size_t needPad = padInts * sizeof(int) +
                         (size_t)N_NODES * DIM * sizeof(float);

  if (ws_size >= needPad) {
    // ---- padded path: 2-dispatch CSR build ----
    int* cnt     = (int*)d_ws;
    int* csr_pad = cnt + N_NODES;
    float* h1    = (float*)(csr_pad + (size_t)N_NODES * CAP);

    // zero cnt AND csr_pad: unwritten slots read as src=0 (valid, discarded)
    hipMemsetAsync(cnt, 0, padInts * sizeof(int), stream);
    fill_csr_pad<<<quadBlocks, 256, 0, stream>>>(
        (const int4*)src, (const int4*)dst, cnt, csr_pad, NQUADS);

    sage_fused<true><<<fusedBlocks, 256, 0, stream>>>(
        x, cnt, csr_pad, Wn1, Ws1, b1, h1, N_NODES);
    sage_fused<true><<<fusedBlocks, 256, 0, stream>>>(
        h1, cnt, csr_pad, Wn2, Ws2, b2, outp, N_NODES);
  } else {
    // ---- legacy path (ws too small for padded layout) ----
    // ws (ints): deg_s[8N] | offs[N+1] | cursor_s[8N] | bsums[512] | csr[E] | h1f
    int* deg_s    = (int*)d_ws;
    int* offs     = deg_s + (size_t)NSHARD * N_NODES;
    int* cursor_s = offs + N_NODES + 1;
    int* bsums    = cursor_s + (size_t)NSHARD * N_NODES;
    int* csr      = bsums + 512;
    float* h1     = (float*)(csr + N_EDGES);

    hipMemsetAsync(deg_s, 0, (size_t)NSHARD * N_NODES * sizeof(int), stream);
    hist_deg_s<<<quadBlocks, 256, 0, stream>>>((const int4*)dst, deg_s, NQUADS);
    block_sums<<<NB, SCAN_BLOCK, 0, stream>>>(deg_s, bsums, N_NODES);
    scan_bsums<<<1, 512, 0, stream>>>(bsums, NB);
    scan_final<<<NB, SCAN_BLOCK, 0, stream>>>(deg_s, bsums, offs, cursor_s, N_NODES);
    fill_csr_s<<<quadBlocks, 256, 0, stream>>>((const int4*)src, (const int4*)dst,
                                               cursor_s, csr, NQUADS);

    sage_fused<false><<<fusedBlocks, 256, 0, stream>>>(
        x, offs, csr, Wn1, Ws1, b1, h1, N_NODES);
    sage_fused<false><<<fusedBlocks, 256, 0, stream>>>(
        h1, offs, csr, Wn2, Ws2, b2, outp, N_NODES);
  }
}

// Round 7
// 382.123 us; speedup vs baseline: 1.0064x; 1.0064x over previous
//
#include <hip/hip_runtime.h>

#define N_NODES 100000
#define N_EDGES 1200000
#define DIM 64
#define SCAN_BLOCK 256
#define NB ((N_NODES + SCAN_BLOCK - 1) / SCAN_BLOCK)  // 391
#define NSHARD 8
#define NQUADS (N_EDGES / 4)  // 300000, exact
#define CAP 40  // padded-CSR row capacity; P(deg>=40 | Poisson(12)) ~1e-11/node

__device__ __forceinline__ float lane_bcast(float v, int k) {
  return __int_as_float(__builtin_amdgcn_readlane(__float_as_int(v), k));
}

// butterfly-sum a float4 across the four 16-lane groups (xor 16, then 32)
__device__ __forceinline__ float4 qsum(float4 v) {
  v.x += __shfl_xor(v.x, 16); v.y += __shfl_xor(v.y, 16);
  v.z += __shfl_xor(v.z, 16); v.w += __shfl_xor(v.w, 16);
  v.x += __shfl_xor(v.x, 32); v.y += __shfl_xor(v.y, 32);
  v.z += __shfl_xor(v.z, 32); v.w += __shfl_xor(v.w, 32);
  return v;
}

// ---- PADDED CSR build: offsets COMPUTED (row n = n*CAP); no hist/scan.
// cnt doubles as cursor and degree. csr_pad pre-zeroed so clamped reads of
// unwritten slots return src=0 (valid node, value discarded via scale=0).
// ROUND-7 CHANGE: all 4 atomicAdds issue BEFORE the 4 dependent stores.
// The old interleaved form (atomic, store, atomic, store...) forced a
// vmcnt(0) drain per atomic -> 4 serial ~700cy round-trips per thread.
// Batched, the 4 RMWs overlap in flight (vmcnt staircase) -> ~1 round-trip.
__global__ __launch_bounds__(256) void fill_csr_pad(
    const int4* __restrict__ src4, const int4* __restrict__ dst4,
    int* __restrict__ cnt, int* __restrict__ csr_pad, int nQuads) {
  int t = blockIdx.x * blockDim.x + threadIdx.x;
  if (t < nQuads) {
    int4 sv = src4[t];
    int4 dv = dst4[t];
    int p0 = atomicAdd(&cnt[dv.x], 1);
    int p1 = atomicAdd(&cnt[dv.y], 1);
    int p2 = atomicAdd(&cnt[dv.z], 1);
    int p3 = atomicAdd(&cnt[dv.w], 1);
    if (p0 < CAP) csr_pad[dv.x * CAP + p0] = sv.x;
    if (p1 < CAP) csr_pad[dv.y * CAP + p1] = sv.y;
    if (p2 < CAP) csr_pad[dv.z * CAP + p2] = sv.z;
    if (p3 < CAP) csr_pad[dv.w * CAP + p3] = sv.w;
  }
}

// ---- LEGACY CSR build (fallback if ws_size too small for padded layout) ---

__global__ __launch_bounds__(256) void hist_deg_s(
    const int4* __restrict__ dst4, int* __restrict__ deg_s, int nQuads) {
  int t = blockIdx.x * blockDim.x + threadIdx.x;
  int shard = blockIdx.x & (NSHARD - 1);
  if (t < nQuads) {
    int4 d = dst4[t];
    int* tbl = deg_s + (size_t)shard * N_NODES;
    atomicAdd(&tbl[d.x], 1);
    atomicAdd(&tbl[d.y], 1);
    atomicAdd(&tbl[d.z], 1);
    atomicAdd(&tbl[d.w], 1);
  }
}

__global__ __launch_bounds__(SCAN_BLOCK) void block_sums(
    const int* __restrict__ deg_s, int* __restrict__ bsums, int n) {
  __shared__ int s[SCAN_BLOCK];
  int i = blockIdx.x * SCAN_BLOCK + threadIdx.x;
  int d = 0;
  if (i < n) {
#pragma unroll
    for (int sh = 0; sh < NSHARD; ++sh) d += deg_s[(size_t)sh * N_NODES + i];
  }
  s[threadIdx.x] = d;
  __syncthreads();
  for (int off = SCAN_BLOCK / 2; off > 0; off >>= 1) {
    if (threadIdx.x < off) s[threadIdx.x] += s[threadIdx.x + off];
    __syncthreads();
  }
  if (threadIdx.x == 0) bsums[blockIdx.x] = s[0];
}

__global__ __launch_bounds__(512) void scan_bsums(int* __restrict__ bsums, int nb) {
  __shared__ int s[512];
  int tid = threadIdx.x;
  s[tid] = (tid < nb) ? bsums[tid] : 0;
  __syncthreads();
  for (int off = 1; off < 512; off <<= 1) {
    int v = (tid >= off) ? s[tid - off] : 0;
    __syncthreads();
    s[tid] += v;
    __syncthreads();
  }
  if (tid < nb) bsums[tid] = (tid == 0) ? 0 : s[tid - 1];  // exclusive base
}

__global__ __launch_bounds__(SCAN_BLOCK) void scan_final(
    const int* __restrict__ deg_s, const int* __restrict__ bbase,
    int* __restrict__ offs, int* __restrict__ cursor_s, int n) {
  __shared__ int s[SCAN_BLOCK];
  int i = blockIdx.x * SCAN_BLOCK + threadIdx.x;
  int ds0 = 0, ds1 = 0, ds2 = 0, ds3 = 0, ds4 = 0, ds5 = 0, ds6 = 0, ds7 = 0;
  int v = 0;
  if (i < n) {
    ds0 = deg_s[0ul * N_NODES + i]; ds1 = deg_s[1ul * N_NODES + i];
    ds2 = deg_s[2ul * N_NODES + i]; ds3 = deg_s[3ul * N_NODES + i];
    ds4 = deg_s[4ul * N_NODES + i]; ds5 = deg_s[5ul * N_NODES + i];
    ds6 = deg_s[6ul * N_NODES + i]; ds7 = deg_s[7ul * N_NODES + i];
    v = ((ds0 + ds1) + (ds2 + ds3)) + ((ds4 + ds5) + (ds6 + ds7));
  }
  s[threadIdx.x] = v;
  __syncthreads();
  for (int off = 1; off < SCAN_BLOCK; off <<= 1) {
    int t = (threadIdx.x >= off) ? s[threadIdx.x - off] : 0;
    __syncthreads();
    s[threadIdx.x] += t;
    __syncthreads();
  }
  int base = bbase[blockIdx.x];
  if (i < n) {
    int run = base + s[threadIdx.x] - v;  // exclusive
    offs[i] = run;
    cursor_s[0ul * N_NODES + i] = run; run += ds0;
    cursor_s[1ul * N_NODES + i] = run; run += ds1;
    cursor_s[2ul * N_NODES + i] = run; run += ds2;
    cursor_s[3ul * N_NODES + i] = run; run += ds3;
    cursor_s[4ul * N_NODES + i] = run; run += ds4;
    cursor_s[5ul * N_NODES + i] = run; run += ds5;
    cursor_s[6ul * N_NODES + i] = run; run += ds6;
    cursor_s[7ul * N_NODES + i] = run;
  }
  if (i == n - 1) offs[n] = base + s[threadIdx.x];
}

__global__ __launch_bounds__(256) void fill_csr_s(
    const int4* __restrict__ src4, const int4* __restrict__ dst4,
    int* __restrict__ cursor_s, int* __restrict__ csr_src, int nQuads) {
  int t = blockIdx.x * blockDim.x + threadIdx.x;
  int shard = blockIdx.x & (NSHARD - 1);
  if (t < nQuads) {
    int4 sv = src4[t];
    int4 dv = dst4[t];
    int* cur = cursor_s + (size_t)shard * N_NODES;
    csr_src[atomicAdd(&cur[dv.x], 1)] = sv.x;
    csr_src[atomicAdd(&cur[dv.y], 1)] = sv.y;
    csr_src[atomicAdd(&cur[dv.z], 1)] = sv.z;
    csr_src[atomicAdd(&cur[dv.w], 1)] = sv.w;
  }
}

// ---- Fused SAGE layer v12 (unchanged from round 6) ------------------------
// Gather: wave = (q=lane>>4, r=lane&15); 2x-unrolled -> 8 edges/node/iter in
// flight + software-pipelined csr prefetch; branch-free mean fold.
// Matvec sources mean straight from A/B via readlane (lane k>>2, component
// k&3, both compile-time) — no transpose stage.
// ROUND-2 LESSON: never use the min-waves arg of __launch_bounds__.
// ROUND-3 LESSON: no occupancy/query APIs inside kernel_launch.
// ROUND-6/7 LESSON: no indexed private arrays, ever.
// Occupancy box: LDS 32768 B -> 5 blocks/CU; VGPR 96 <= 102 -> 5 waves/SIMD.
template <bool PADDED>
__global__ __launch_bounds__(256) void sage_fused(
    const float* __restrict__ xin, const int* __restrict__ offs_or_cnt,
    const int* __restrict__ csr_src, const float* __restrict__ Wn,
    const float* __restrict__ Ws, const float* __restrict__ bias,
    float* __restrict__ out, int nNodes) {
  __shared__ float2 sW[DIM * DIM];  // [k][j] -> (wn, ws), 32768 B exactly
  {
    const float4* Wn4 = reinterpret_cast<const float4*>(Wn);
    const float4* Ws4 = reinterpret_cast<const float4*>(Ws);
    for (int i = threadIdx.x; i < DIM * DIM / 4; i += 256) {
      float4 a = Wn4[i];
      float4 b = Ws4[i];
      float2* d = &sW[i * 4];  // i = k*16 + jq -> element k*64 + 4*jq
      d[0] = make_float2(a.x, b.x);
      d[1] = make_float2(a.y, b.y);
      d[2] = make_float2(a.z, b.z);
      d[3] = make_float2(a.w, b.w);
    }
  }
  __syncthreads();

  const float4* xr = reinterpret_cast<const float4*>(xin);
  int lane = threadIdx.x & 63;
  int q = lane >> 4;   // edge subgroup 0..3
  int r = lane & 15;   // float4 column 0..15
  int j = lane;        // output dim
  int w = threadIdx.x >> 6;
  float bj = bias[j];
  int gw = blockIdx.x * 4 + w;
  int nw = gridDim.x * 4;

  for (int p = gw; 2 * p < nNodes; p += nw) {
    int pu = __builtin_amdgcn_readfirstlane(p);  // wave-uniform -> s_loads
    int n0 = 2 * pu, n1 = 2 * pu + 1;
    int e0a, e1a, e0b, e1b;
    float inv0, inv1;
    if (PADDED) {
      int d0 = offs_or_cnt[n0], d1 = offs_or_cnt[n1];
      e0a = n0 * CAP; e1a = e0a + min(d0, CAP);
      e0b = e0a + CAP; e1b = e0b + min(d1, CAP);
      inv0 = 1.0f / fmaxf((float)d0, 1.0f);  // true count, matches reference
      inv1 = 1.0f / fmaxf((float)d1, 1.0f);
    } else {
      e0a = offs_or_cnt[n0]; e0b = offs_or_cnt[n1]; e1b = offs_or_cnt[n1 + 1];
      e1a = e0b;  // offs[n0+1] == offs[n1]
      inv0 = 1.0f / fmaxf((float)(e1a - e0a), 1.0f);
      inv1 = 1.0f / fmaxf((float)(e1b - e0b), 1.0f);
    }
    float self0 = xin[(size_t)n0 * DIM + j];
    float self1 = xin[(size_t)n1 * DIM + j];

    float4 A = {0, 0, 0, 0}, B = {0, 0, 0, 0};
    int ea0 = e0a + q, ea1 = e0a + q + 4;
    int eb0 = e0b + q, eb1 = e0b + q + 4;
    int rem = max(e1a - e0a, e1b - e0b);
    // prologue: csr index loads for iteration 0 (clamped -> always valid)
    int sa0 = csr_src[max(min(ea0, e1a - 1), 0)];
    int sa1 = csr_src[max(min(ea1, e1a - 1), 0)];
    int sb0 = csr_src[max(min(eb0, e1b - 1), 0)];
    int sb1 = csr_src[max(min(eb1, e1b - 1), 0)];
    while (rem > 0) {
      // issue all 8 x-row gathers for the current 8 edges
      float4 va0 = xr[(size_t)sa0 * 16 + r];
      float4 va1 = xr[(size_t)sa1 * 16 + r];
      float4 vb0 = xr[(size_t)sb0 * 16 + r];
      float4 vb1 = xr[(size_t)sb1 * 16 + r];
      float fa0 = (ea0 < e1a) ? inv0 : 0.0f;
      float fa1 = (ea1 < e1a) ? inv0 : 0.0f;
      float fb0 = (eb0 < e1b) ? inv1 : 0.0f;
      float fb1 = (eb1 < e1b) ? inv1 : 0.0f;
      ea0 += 8; ea1 += 8; eb0 += 8; eb1 += 8; rem -= 8;
      // prefetch next iteration's csr indices while x rows are in flight
      int na0 = csr_src[max(min(ea0, e1a - 1), 0)];
      int na1 = csr_src[max(min(ea1, e1a - 1), 0)];
      int nb0 = csr_src[max(min(eb0, e1b - 1), 0)];
      int nb1 = csr_src[max(min(eb1, e1b - 1), 0)];
      A.x = fmaf(va0.x, fa0, A.x); A.y = fmaf(va0.y, fa0, A.y);
      A.z = fmaf(va0.z, fa0, A.z); A.w = fmaf(va0.w, fa0, A.w);
      A.x = fmaf(va1.x, fa1, A.x); A.y = fmaf(va1.y, fa1, A.y);
      A.z = fmaf(va1.z, fa1, A.z); A.w = fmaf(va1.w, fa1, A.w);
      B.x = fmaf(vb0.x, fb0, B.x); B.y = fmaf(vb0.y, fb0, B.y);
      B.z = fmaf(vb0.z, fb0, B.z); B.w = fmaf(vb0.w, fb0, B.w);
      B.x = fmaf(vb1.x, fb1, B.x); B.y = fmaf(vb1.y, fb1, B.y);
      B.z = fmaf(vb1.z, fb1, B.z); B.w = fmaf(vb1.w, fb1, B.w);
      sa0 = na0; sa1 = na1; sb0 = nb0; sb1 = nb1;
    }
    A = qsum(A);  // every lane now holds the FULL mean for dims [4r,4r+4)
    B = qsum(B);

    // matvec: 4 independent chains; ONE b64 weight read per k; mean sourced
    // straight from A/B via readlane (lane k>>2, component k&3 — both
    // compile-time in the unrolled loop). No transpose stage.
    float a0n = bj, a0s = 0.f, a1n = bj, a1s = 0.f;
#pragma unroll
    for (int kk = 0; kk < DIM / 4; ++kk) {
      {
        float2 wk = sW[(4 * kk + 0) * DIM + j];
        a0n = fmaf(lane_bcast(A.x, kk), wk.x, a0n);
        a0s = fmaf(lane_bcast(self0, 4 * kk + 0), wk.y, a0s);
        a1n = fmaf(lane_bcast(B.x, kk), wk.x, a1n);
        a1s = fmaf(lane_bcast(self1, 4 * kk + 0), wk.y, a1s);
      }
      {
        float2 wk = sW[(4 * kk + 1) * DIM + j];
        a0n = fmaf(lane_bcast(A.y, kk), wk.x, a0n);
        a0s = fmaf(lane_bcast(self0, 4 * kk + 1), wk.y, a0s);
        a1n = fmaf(lane_bcast(B.y, kk), wk.x, a1n);
        a1s = fmaf(lane_bcast(self1, 4 * kk + 1), wk.y, a1s);
      }
      {
        float2 wk = sW[(4 * kk + 2) * DIM + j];
        a0n = fmaf(lane_bcast(A.z, kk), wk.x, a0n);
        a0s = fmaf(lane_bcast(self0, 4 * kk + 2), wk.y, a0s);
        a1n = fmaf(lane_bcast(B.z, kk), wk.x, a1n);
        a1s = fmaf(lane_bcast(self1, 4 * kk + 2), wk.y, a1s);
      }
      {
        float2 wk = sW[(4 * kk + 3) * DIM + j];
        a0n = fmaf(lane_bcast(A.w, kk), wk.x, a0n);
        a0s = fmaf(lane_bcast(self0, 4 * kk + 3), wk.y, a0s);
        a1n = fmaf(lane_bcast(B.w, kk), wk.x, a1n);
        a1s = fmaf(lane_bcast(self1, 4 * kk + 3), wk.y, a1s);
      }
    }
    out[(size_t)n0 * DIM + j] = fmaxf(a0n + a0s, 0.0f);
    out[(size_t)n1 * DIM + j] = fmaxf(a1n + a1s, 0.0f);
  }
}

// Residency ground truth, queried ONCE at library load — before any stream
// capture exists (round-3 lesson). Both instantiations share the footprint.
static int g_fusedBlocks = 0;
__attribute__((constructor)) static void init_fused_blocks() {
  int occ = 0;
  if (hipOccupancyMaxActiveBlocksPerMultiprocessor(&occ, sage_fused<true>, 256, 0)
          != hipSuccess || occ < 1)
    occ = 4;  // conservative fallback: 4/CU always resident
  g_fusedBlocks = occ * 256;  // blocks/CU * 256 CUs, all resident at t=0
}

extern "C" void kernel_launch(void* const* d_in, const int* in_sizes, int n_in,
                              void* d_out, int out_size, void* d_ws, size_t ws_size,
                              hipStream_t stream) {
  const float* x   = (const float*)d_in[0];
  const int*   ei  = (const int*)d_in[1];
  const float* Wn1 = (const float*)d_in[2];
  const float* Ws1 = (const float*)d_in[3];
  const float* b1  = (const float*)d_in[4];
  const float* Wn2 = (const float*)d_in[5];
  const float* Ws2 = (const float*)d_in[6];
  const float* b2  = (const float*)d_in[7];
  const int* src = ei;
  const int* dst = ei + N_EDGES;

  const int quadBlocks = (NQUADS + 255) / 256;  // 1172
  const int fusedBlocks = (g_fusedBlocks > 0) ? g_fusedBlocks : 1024;
  float* outp = (float*)d_out;

  // Padded layout (ints): cnt[N] | csr_pad[N*CAP] | h1[N*64]f
  const size_t padInts = (size_t)N_NODES + (size_t)N_NODES * CAP;
  const size_t needPad = padInts * sizeof(int) +
                         (size_t)N_NODES * DIM * sizeof(float);

  if (ws_size >= needPad) {
    // ---- padded path: 2-dispatch CSR build ----
    int* cnt     = (int*)d_ws;
    int* csr_pad = cnt + N_NODES;
    float* h1    = (float*)(csr_pad + (size_t)N_NODES * CAP);

    // zero cnt AND csr_pad: unwritten slots read as src=0 (valid, discarded)
    hipMemsetAsync(cnt, 0, padInts * sizeof(int), stream);
    fill_csr_pad<<<quadBlocks, 256, 0, stream>>>(
        (const int4*)src, (const int4*)dst, cnt, csr_pad, NQUADS);

    sage_fused<true><<<fusedBlocks, 256, 0, stream>>>(
        x, cnt, csr_pad, Wn1, Ws1, b1, h1, N_NODES);
    sage_fused<true><<<fusedBlocks, 256, 0, stream>>>(
        h1, cnt, csr_pad, Wn2, Ws2, b2, outp, N_NODES);
  } else {
    // ---- legacy path (ws too small for padded layout) ----
    // ws (ints): deg_s[8N] | offs[N+1] | cursor_s[8N] | bsums[512] | csr[E] | h1f
    int* deg_s    = (int*)d_ws;
    int* offs     = deg_s + (size_t)NSHARD * N_NODES;
    int* cursor_s = offs + N_NODES + 1;
    int* bsums    = cursor_s + (size_t)NSHARD * N_NODES;
    int* csr      = bsums + 512;
    float* h1     = (float*)(csr + N_EDGES);

    hipMemsetAsync(deg_s, 0, (size_t)NSHARD * N_NODES * sizeof(int), stream);
    hist_deg_s<<<quadBlocks, 256, 0, stream>>>((const int4*)dst, deg_s, NQUADS);
    block_sums<<<NB, SCAN_BLOCK, 0, stream>>>(deg_s, bsums, N_NODES);
    scan_bsums<<<1, 512, 0, stream>>>(bsums, NB);
    scan_final<<<NB, SCAN_BLOCK, 0, stream>>>(deg_s, bsums, offs, cursor_s, N_NODES);
    fill_csr_s<<<quadBlocks, 256, 0, stream>>>((const int4*)src, (const int4*)dst,
                                               cursor_s, csr, NQUADS);

    sage_fused<false><<<fusedBlocks, 256, 0, stream>>>(
        x, offs, csr, Wn1, Ws1, b1, h1, N_NODES);
    sage_fused<false><<<fusedBlocks, 256, 0, stream>>>(
        h1, offs, csr, Wn2, Ws2, b2, outp, N_NODES);
  }
}

// Round 8
// 379.712 us; speedup vs baseline: 1.0128x; 1.0064x over previous
//
#include <hip/hip_runtime.h>

#define N_NODES 100000
#define N_EDGES 1200000
#define DIM 64
#define SCAN_BLOCK 256
#define NB ((N_NODES + SCAN_BLOCK - 1) / SCAN_BLOCK)  // 391
#define NSHARD 8
#define NQUADS (N_EDGES / 4)  // 300000, exact
#define CAP 40  // padded-CSR row capacity; P(deg>=40 | Poisson(12)) ~1e-11/node

__device__ __forceinline__ float lane_bcast(float v, int k) {
  return __int_as_float(__builtin_amdgcn_readlane(__float_as_int(v), k));
}

// butterfly-sum a float4 across the four 16-lane groups (xor 16, then 32)
__device__ __forceinline__ float4 qsum(float4 v) {
  v.x += __shfl_xor(v.x, 16); v.y += __shfl_xor(v.y, 16);
  v.z += __shfl_xor(v.z, 16); v.w += __shfl_xor(v.w, 16);
  v.x += __shfl_xor(v.x, 32); v.y += __shfl_xor(v.y, 32);
  v.z += __shfl_xor(v.z, 32); v.w += __shfl_xor(v.w, 32);
  return v;
}

// ---- PADDED CSR build: offsets COMPUTED (row n = n*CAP); no hist/scan.
// cnt doubles as cursor and degree.
// ROUND-8 CHANGE: csr_pad is NO LONGER pre-zeroed (memset 16.8MB -> 0.4MB).
// Safety moved to the consumer: sage_fused clamps every loaded index to
// [0, N), so garbage in unwritten slots yields a valid (finite) x row whose
// contribution is exactly discarded via scale=0. Stores are non-temporal:
// the 16MB scatter has zero reuse inside fill and would otherwise churn the
// L2 lines the cnt atomics want hot.
// ROUND-7 LESSON: batching the 4 atomics before the stores was NEUTRAL —
// both pointers are __restrict__ so the compiler had already hoisted them;
// fill is throughput-bound on random RMW+scatter, not on chain latency.
__global__ __launch_bounds__(256) void fill_csr_pad(
    const int4* __restrict__ src4, const int4* __restrict__ dst4,
    int* __restrict__ cnt, int* __restrict__ csr_pad, int nQuads) {
  int t = blockIdx.x * blockDim.x + threadIdx.x;
  if (t < nQuads) {
    int4 sv = src4[t];
    int4 dv = dst4[t];
    int p0 = atomicAdd(&cnt[dv.x], 1);
    int p1 = atomicAdd(&cnt[dv.y], 1);
    int p2 = atomicAdd(&cnt[dv.z], 1);
    int p3 = atomicAdd(&cnt[dv.w], 1);
    if (p0 < CAP) __builtin_nontemporal_store(sv.x, &csr_pad[dv.x * CAP + p0]);
    if (p1 < CAP) __builtin_nontemporal_store(sv.y, &csr_pad[dv.y * CAP + p1]);
    if (p2 < CAP) __builtin_nontemporal_store(sv.z, &csr_pad[dv.z * CAP + p2]);
    if (p3 < CAP) __builtin_nontemporal_store(sv.w, &csr_pad[dv.w * CAP + p3]);
  }
}

// ---- LEGACY CSR build (fallback if ws_size too small for padded layout) ---

__global__ __launch_bounds__(256) void hist_deg_s(
    const int4* __restrict__ dst4, int* __restrict__ deg_s, int nQuads) {
  int t = blockIdx.x * blockDim.x + threadIdx.x;
  int shard = blockIdx.x & (NSHARD - 1);
  if (t < nQuads) {
    int4 d = dst4[t];
    int* tbl = deg_s + (size_t)shard * N_NODES;
    atomicAdd(&tbl[d.x], 1);
    atomicAdd(&tbl[d.y], 1);
    atomicAdd(&tbl[d.z], 1);
    atomicAdd(&tbl[d.w], 1);
  }
}

__global__ __launch_bounds__(SCAN_BLOCK) void block_sums(
    const int* __restrict__ deg_s, int* __restrict__ bsums, int n) {
  __shared__ int s[SCAN_BLOCK];
  int i = blockIdx.x * SCAN_BLOCK + threadIdx.x;
  int d = 0;
  if (i < n) {
#pragma unroll
    for (int sh = 0; sh < NSHARD; ++sh) d += deg_s[(size_t)sh * N_NODES + i];
  }
  s[threadIdx.x] = d;
  __syncthreads();
  for (int off = SCAN_BLOCK / 2; off > 0; off >>= 1) {
    if (threadIdx.x < off) s[threadIdx.x] += s[threadIdx.x + off];
    __syncthreads();
  }
  if (threadIdx.x == 0) bsums[blockIdx.x] = s[0];
}

__global__ __launch_bounds__(512) void scan_bsums(int* __restrict__ bsums, int nb) {
  __shared__ int s[512];
  int tid = threadIdx.x;
  s[tid] = (tid < nb) ? bsums[tid] : 0;
  __syncthreads();
  for (int off = 1; off < 512; off <<= 1) {
    int v = (tid >= off) ? s[tid - off] : 0;
    __syncthreads();
    s[tid] += v;
    __syncthreads();
  }
  if (tid < nb) bsums[tid] = (tid == 0) ? 0 : s[tid - 1];  // exclusive base
}

__global__ __launch_bounds__(SCAN_BLOCK) void scan_final(
    const int* __restrict__ deg_s, const int* __restrict__ bbase,
    int* __restrict__ offs, int* __restrict__ cursor_s, int n) {
  __shared__ int s[SCAN_BLOCK];
  int i = blockIdx.x * SCAN_BLOCK + threadIdx.x;
  int ds0 = 0, ds1 = 0, ds2 = 0, ds3 = 0, ds4 = 0, ds5 = 0, ds6 = 0, ds7 = 0;
  int v = 0;
  if (i < n) {
    ds0 = deg_s[0ul * N_NODES + i]; ds1 = deg_s[1ul * N_NODES + i];
    ds2 = deg_s[2ul * N_NODES + i]; ds3 = deg_s[3ul * N_NODES + i];
    ds4 = deg_s[4ul * N_NODES + i]; ds5 = deg_s[5ul * N_NODES + i];
    ds6 = deg_s[6ul * N_NODES + i]; ds7 = deg_s[7ul * N_NODES + i];
    v = ((ds0 + ds1) + (ds2 + ds3)) + ((ds4 + ds5) + (ds6 + ds7));
  }
  s[threadIdx.x] = v;
  __syncthreads();
  for (int off = 1; off < SCAN_BLOCK; off <<= 1) {
    int t = (threadIdx.x >= off) ? s[threadIdx.x - off] : 0;
    __syncthreads();
    s[threadIdx.x] += t;
    __syncthreads();
  }
  int base = bbase[blockIdx.x];
  if (i < n) {
    int run = base + s[threadIdx.x] - v;  // exclusive
    offs[i] = run;
    cursor_s[0ul * N_NODES + i] = run; run += ds0;
    cursor_s[1ul * N_NODES + i] = run; run += ds1;
    cursor_s[2ul * N_NODES + i] = run; run += ds2;
    cursor_s[3ul * N_NODES + i] = run; run += ds3;
    cursor_s[4ul * N_NODES + i] = run; run += ds4;
    cursor_s[5ul * N_NODES + i] = run; run += ds5;
    cursor_s[6ul * N_NODES + i] = run; run += ds6;
    cursor_s[7ul * N_NODES + i] = run;
  }
  if (i == n - 1) offs[n] = base + s[threadIdx.x];
}

__global__ __launch_bounds__(256) void fill_csr_s(
    const int4* __restrict__ src4, const int4* __restrict__ dst4,
    int* __restrict__ cursor_s, int* __restrict__ csr_src, int nQuads) {
  int t = blockIdx.x * blockDim.x + threadIdx.x;
  int shard = blockIdx.x & (NSHARD - 1);
  if (t < nQuads) {
    int4 sv = src4[t];
    int4 dv = dst4[t];
    int* cur = cursor_s + (size_t)shard * N_NODES;
    csr_src[atomicAdd(&cur[dv.x], 1)] = sv.x;
    csr_src[atomicAdd(&cur[dv.y], 1)] = sv.y;
    csr_src[atomicAdd(&cur[dv.z], 1)] = sv.z;
    csr_src[atomicAdd(&cur[dv.w], 1)] = sv.w;
  }
}

// ---- Fused SAGE layer v13 -------------------------------------------------
// Gather: wave = (q=lane>>4, r=lane&15); 2x-unrolled -> 8 edges/node/iter in
// flight + software-pipelined csr prefetch; branch-free mean fold.
// Matvec sources mean straight from A/B via readlane (lane k>>2, component
// k&3, both compile-time) — no transpose stage.
// ROUND-8 CHANGE (PADDED only): loaded csr indices are value-clamped to
// [0, N) because csr_pad is no longer zeroed. Clamped garbage reads a valid
// finite x row whose contribution is exactly zeroed by the fold scale.
// ROUND-2 LESSON: never use the min-waves arg of __launch_bounds__.
// ROUND-3 LESSON: no occupancy/query APIs inside kernel_launch.
// ROUND-6/7 LESSON: no indexed private arrays, ever.
// Occupancy box: LDS 32768 B -> 5 blocks/CU; VGPR must stay <= 102.
template <bool PADDED>
__global__ __launch_bounds__(256) void sage_fused(
    const float* __restrict__ xin, const int* __restrict__ offs_or_cnt,
    const int* __restrict__ csr_src, const float* __restrict__ Wn,
    const float* __restrict__ Ws, const float* __restrict__ bias,
    float* __restrict__ out, int nNodes) {
  __shared__ float2 sW[DIM * DIM];  // [k][j] -> (wn, ws), 32768 B exactly
  {
    const float4* Wn4 = reinterpret_cast<const float4*>(Wn);
    const float4* Ws4 = reinterpret_cast<const float4*>(Ws);
    for (int i = threadIdx.x; i < DIM * DIM / 4; i += 256) {
      float4 a = Wn4[i];
      float4 b = Ws4[i];
      float2* d = &sW[i * 4];  // i = k*16 + jq -> element k*64 + 4*jq
      d[0] = make_float2(a.x, b.x);
      d[1] = make_float2(a.y, b.y);
      d[2] = make_float2(a.z, b.z);
      d[3] = make_float2(a.w, b.w);
    }
  }
  __syncthreads();

  const float4* xr = reinterpret_cast<const float4*>(xin);
  int lane = threadIdx.x & 63;
  int q = lane >> 4;   // edge subgroup 0..3
  int r = lane & 15;   // float4 column 0..15
  int j = lane;        // output dim
  int w = threadIdx.x >> 6;
  float bj = bias[j];
  const int nm1 = nNodes - 1;
  int gw = blockIdx.x * 4 + w;
  int nw = gridDim.x * 4;

  for (int p = gw; 2 * p < nNodes; p += nw) {
    int pu = __builtin_amdgcn_readfirstlane(p);  // wave-uniform -> s_loads
    int n0 = 2 * pu, n1 = 2 * pu + 1;
    int e0a, e1a, e0b, e1b;
    float inv0, inv1;
    if (PADDED) {
      int d0 = offs_or_cnt[n0], d1 = offs_or_cnt[n1];
      e0a = n0 * CAP; e1a = e0a + min(d0, CAP);
      e0b = e0a + CAP; e1b = e0b + min(d1, CAP);
      inv0 = 1.0f / fmaxf((float)d0, 1.0f);  // true count, matches reference
      inv1 = 1.0f / fmaxf((float)d1, 1.0f);
    } else {
      e0a = offs_or_cnt[n0]; e0b = offs_or_cnt[n1]; e1b = offs_or_cnt[n1 + 1];
      e1a = e0b;  // offs[n0+1] == offs[n1]
      inv0 = 1.0f / fmaxf((float)(e1a - e0a), 1.0f);
      inv1 = 1.0f / fmaxf((float)(e1b - e0b), 1.0f);
    }
    float self0 = xin[(size_t)n0 * DIM + j];
    float self1 = xin[(size_t)n1 * DIM + j];

    float4 A = {0, 0, 0, 0}, B = {0, 0, 0, 0};
    int ea0 = e0a + q, ea1 = e0a + q + 4;
    int eb0 = e0b + q, eb1 = e0b + q + 4;
    int rem = max(e1a - e0a, e1b - e0b);
    // prologue: csr index loads for iteration 0 (clamped -> always valid)
    int sa0 = csr_src[max(min(ea0, e1a - 1), 0)];
    int sa1 = csr_src[max(min(ea1, e1a - 1), 0)];
    int sb0 = csr_src[max(min(eb0, e1b - 1), 0)];
    int sb1 = csr_src[max(min(eb1, e1b - 1), 0)];
    if (PADDED) {  // unzeroed csr_pad: clamp values to valid node range
      sa0 = min(max(sa0, 0), nm1); sa1 = min(max(sa1, 0), nm1);
      sb0 = min(max(sb0, 0), nm1); sb1 = min(max(sb1, 0), nm1);
    }
    while (rem > 0) {
      // issue all 8 x-row gathers for the current 8 edges
      float4 va0 = xr[(size_t)sa0 * 16 + r];
      float4 va1 = xr[(size_t)sa1 * 16 + r];
      float4 vb0 = xr[(size_t)sb0 * 16 + r];
      float4 vb1 = xr[(size_t)sb1 * 16 + r];
      float fa0 = (ea0 < e1a) ? inv0 : 0.0f;
      float fa1 = (ea1 < e1a) ? inv0 : 0.0f;
      float fb0 = (eb0 < e1b) ? inv1 : 0.0f;
      float fb1 = (eb1 < e1b) ? inv1 : 0.0f;
      ea0 += 8; ea1 += 8; eb0 += 8; eb1 += 8; rem -= 8;
      // prefetch next iteration's csr indices while x rows are in flight
      int na0 = csr_src[max(min(ea0, e1a - 1), 0)];
      int na1 = csr_src[max(min(ea1, e1a - 1), 0)];
      int nb0 = csr_src[max(min(eb0, e1b - 1), 0)];
      int nb1 = csr_src[max(min(eb1, e1b - 1), 0)];
      if (PADDED) {
        na0 = min(max(na0, 0), nm1); na1 = min(max(na1, 0), nm1);
        nb0 = min(max(nb0, 0), nm1); nb1 = min(max(nb1, 0), nm1);
      }
      A.x = fmaf(va0.x, fa0, A.x); A.y = fmaf(va0.y, fa0, A.y);
      A.z = fmaf(va0.z, fa0, A.z); A.w = fmaf(va0.w, fa0, A.w);
      A.x = fmaf(va1.x, fa1, A.x); A.y = fmaf(va1.y, fa1, A.y);
      A.z = fmaf(va1.z, fa1, A.z); A.w = fmaf(va1.w, fa1, A.w);
      B.x = fmaf(vb0.x, fb0, B.x); B.y = fmaf(vb0.y, fb0, B.y);
      B.z = fmaf(vb0.z, fb0, B.z); B.w = fmaf(vb0.w, fb0, B.w);
      B.x = fmaf(vb1.x, fb1, B.x); B.y = fmaf(vb1.y, fb1, B.y);
      B.z = fmaf(vb1.z, fb1, B.z); B.w = fmaf(vb1.w, fb1, B.w);
      sa0 = na0; sa1 = na1; sb0 = nb0; sb1 = nb1;
    }
    A = qsum(A);  // every lane now holds the FULL mean for dims [4r,4r+4)
    B = qsum(B);

    // matvec: 4 independent chains; ONE b64 weight read per k; mean sourced
    // straight from A/B via readlane (lane k>>2, component k&3 — both
    // compile-time in the unrolled loop). No transpose stage.
    float a0n = bj, a0s = 0.f, a1n = bj, a1s = 0.f;
#pragma unroll
    for (int kk = 0; kk < DIM / 4; ++kk) {
      {
        float2 wk = sW[(4 * kk + 0) * DIM + j];
        a0n = fmaf(lane_bcast(A.x, kk), wk.x, a0n);
        a0s = fmaf(lane_bcast(self0, 4 * kk + 0), wk.y, a0s);
        a1n = fmaf(lane_bcast(B.x, kk), wk.x, a1n);
        a1s = fmaf(lane_bcast(self1, 4 * kk + 0), wk.y, a1s);
      }
      {
        float2 wk = sW[(4 * kk + 1) * DIM + j];
        a0n = fmaf(lane_bcast(A.y, kk), wk.x, a0n);
        a0s = fmaf(lane_bcast(self0, 4 * kk + 1), wk.y, a0s);
        a1n = fmaf(lane_bcast(B.y, kk), wk.x, a1n);
        a1s = fmaf(lane_bcast(self1, 4 * kk + 1), wk.y, a1s);
      }
      {
        float2 wk = sW[(4 * kk + 2) * DIM + j];
        a0n = fmaf(lane_bcast(A.z, kk), wk.x, a0n);
        a0s = fmaf(lane_bcast(self0, 4 * kk + 2), wk.y, a0s);
        a1n = fmaf(lane_bcast(B.z, kk), wk.x, a1n);
        a1s = fmaf(lane_bcast(self1, 4 * kk + 2), wk.y, a1s);
      }
      {
        float2 wk = sW[(4 * kk + 3) * DIM + j];
        a0n = fmaf(lane_bcast(A.w, kk), wk.x, a0n);
        a0s = fmaf(lane_bcast(self0, 4 * kk + 3), wk.y, a0s);
        a1n = fmaf(lane_bcast(B.w, kk), wk.x, a1n);
        a1s = fmaf(lane_bcast(self1, 4 * kk + 3), wk.y, a1s);
      }
    }
    out[(size_t)n0 * DIM + j] = fmaxf(a0n + a0s, 0.0f);
    out[(size_t)n1 * DIM + j] = fmaxf(a1n + a1s, 0.0f);
  }
}

// Residency ground truth, queried ONCE at library load — before any stream
// capture exists (round-3 lesson). Both instantiations share the footprint.
static int g_fusedBlocks = 0;
__attribute__((constructor)) static void init_fused_blocks() {
  int occ = 0;
  if (hipOccupancyMaxActiveBlocksPerMultiprocessor(&occ, sage_fused<true>, 256, 0)
          != hipSuccess || occ < 1)
    occ = 4;  // conservative fallback: 4/CU always resident
  g_fusedBlocks = occ * 256;  // blocks/CU * 256 CUs, all resident at t=0
}

extern "C" void kernel_launch(void* const* d_in, const int* in_sizes, int n_in,
                              void* d_out, int out_size, void* d_ws, size_t ws_size,
                              hipStream_t stream) {
  const float* x   = (const float*)d_in[0];
  const int*   ei  = (const int*)d_in[1];
  const float* Wn1 = (const float*)d_in[2];
  const float* Ws1 = (const float*)d_in[3];
  const float* b1  = (const float*)d_in[4];
  const float* Wn2 = (const float*)d_in[5];
  const float* Ws2 = (const float*)d_in[6];
  const float* b2  = (const float*)d_in[7];
  const int* src = ei;
  const int* dst = ei + N_EDGES;

  const int quadBlocks = (NQUADS + 255) / 256;  // 1172
  const int fusedBlocks = (g_fusedBlocks > 0) ? g_fusedBlocks : 1024;
  float* outp = (float*)d_out;

  // Padded layout (ints): cnt[N] | csr_pad[N*CAP] | h1[N*64]f
  const size_t padInts = (size_t)N_NODES + (size_t)N_NODES * CAP;
  const size_t needPad = padInts * sizeof(int) +
                         (size_t)N_NODES * DIM * sizeof(float);

  if (ws_size >= needPad) {
    // ---- padded path: 2-dispatch CSR build ----
    int* cnt     = (int*)d_ws;
    int* csr_pad = cnt + N_NODES;
    float* h1    = (float*)(csr_pad + (size_t)N_NODES * CAP);

    // ROUND-8: zero ONLY cnt (0.4MB, was 16.8MB) — unwritten csr_pad slots
    // are handled by the consumer's index value-clamp.
    hipMemsetAsync(cnt, 0, (size_t)N_NODES * sizeof(int), stream);
    fill_csr_pad<<<quadBlocks, 256, 0, stream>>>(
        (const int4*)src, (const int4*)dst, cnt, csr_pad, NQUADS);

    sage_fused<true><<<fusedBlocks, 256, 0, stream>>>(
        x, cnt, csr_pad, Wn1, Ws1, b1, h1, N_NODES);
    sage_fused<true><<<fusedBlocks, 256, 0, stream>>>(
        h1, cnt, csr_pad, Wn2, Ws2, b2, outp, N_NODES);
  } else {
    // ---- legacy path (ws too small for padded layout) ----
    // ws (ints): deg_s[8N] | offs[N+1] | cursor_s[8N] | bsums[512] | csr[E] | h1f
    int* deg_s    = (int*)d_ws;
    int* offs     = deg_s + (size_t)NSHARD * N_NODES;
    int* cursor_s = offs + N_NODES + 1;
    int* bsums    = cursor_s + (size_t)NSHARD * N_NODES;
    int* csr      = bsums + 512;
    float* h1     = (float*)(csr + N_EDGES);

    hipMemsetAsync(deg_s, 0, (size_t)NSHARD * N_NODES * sizeof(int), stream);
    hist_deg_s<<<quadBlocks, 256, 0, stream>>>((const int4*)dst, deg_s, NQUADS);
    block_sums<<<NB, SCAN_BLOCK, 0, stream>>>(deg_s, bsums, N_NODES);
    scan_bsums<<<1, 512, 0, stream>>>(bsums, NB);
    scan_final<<<NB, SCAN_BLOCK, 0, stream>>>(deg_s, bsums, offs, cursor_s, N_NODES);
    fill_csr_s<<<quadBlocks, 256, 0, stream>>>((const int4*)src, (const int4*)dst,
                                               cursor_s, csr, NQUADS);

    sage_fused<false><<<fusedBlocks, 256, 0, stream>>>(
        x, offs, csr, Wn1, Ws1, b1, h1, N_NODES);
    sage_fused<false><<<fusedBlocks, 256, 0, stream>>>(
        h1, offs, csr, Wn2, Ws2, b2, outp, N_NODES);
  }
}